// Round 7
// baseline (720.974 us; speedup 1.0000x reference)
//
#include <hip/hip_runtime.h>
#include <hip/hip_fp16.h>
#include <hip/hip_cooperative_groups.h>

namespace cg = cooperative_groups;

#define CCH 64
#define NBLK 128        // phase-A partition blocks
#define BKT  256        // nodes per bucket

// ---------------- Phase A: partitioned counting sort of edges by dst ----------------

__global__ void countA(const int* __restrict__ dst, int* __restrict__ cntmat,
                       int E, int chunk, int B) {
    __shared__ int h[512];
    int t = threadIdx.x, blk = blockIdx.x;
    for (int i = t; i < B; i += 256) h[i] = 0;
    __syncthreads();
    int e0 = blk * chunk, e1 = min(e0 + chunk, E);
    for (int e = e0 + t; e < e1; e += 256) atomicAdd(&h[dst[e] >> 8], 1);
    __syncthreads();
    for (int i = t; i < B; i += 256) cntmat[i * NBLK + blk] = h[i];
}

// Two-level exclusive scan (1024 elems / block)
__global__ void scan1(const int* __restrict__ cnt, int* __restrict__ part,
                      int* __restrict__ bsum, int N) {
    __shared__ int s[256];
    int t = threadIdx.x;
    int base = blockIdx.x * 1024 + t * 4;
    int v0 = (base + 0 < N) ? cnt[base + 0] : 0;
    int v1 = (base + 1 < N) ? cnt[base + 1] : 0;
    int v2 = (base + 2 < N) ? cnt[base + 2] : 0;
    int v3 = (base + 3 < N) ? cnt[base + 3] : 0;
    s[t] = v0 + v1 + v2 + v3;
    __syncthreads();
    for (int off = 1; off < 256; off <<= 1) {
        int xx = (t >= off) ? s[t - off] : 0;
        __syncthreads();
        s[t] += xx;
        __syncthreads();
    }
    int excl = (t == 0) ? 0 : s[t - 1];
    if (t == 255) bsum[blockIdx.x] = s[255];
    if (base + 0 < N) part[base + 0] = excl;
    if (base + 1 < N) part[base + 1] = excl + v0;
    if (base + 2 < N) part[base + 2] = excl + v0 + v1;
    if (base + 3 < N) part[base + 3] = excl + v0 + v1 + v2;
}

__global__ void scan2(int* __restrict__ bsum, int NB) {
    __shared__ int s[256];
    int t = threadIdx.x;
    int base = t * 4;
    int v0 = (base + 0 < NB) ? bsum[base + 0] : 0;
    int v1 = (base + 1 < NB) ? bsum[base + 1] : 0;
    int v2 = (base + 2 < NB) ? bsum[base + 2] : 0;
    int v3 = (base + 3 < NB) ? bsum[base + 3] : 0;
    s[t] = v0 + v1 + v2 + v3;
    __syncthreads();
    for (int off = 1; off < 256; off <<= 1) {
        int xx = (t >= off) ? s[t - off] : 0;
        __syncthreads();
        s[t] += xx;
        __syncthreads();
    }
    int excl = (t == 0) ? 0 : s[t - 1];
    if (base + 0 < NB) bsum[base + 0] = excl;
    if (base + 1 < NB) bsum[base + 1] = excl + v0;
    if (base + 2 < NB) bsum[base + 2] = excl + v0 + v1;
    if (base + 3 < NB) bsum[base + 3] = excl + v0 + v1 + v2;
}

// partition: write (src<<8 | dst&255) into per-(block,bucket) exclusive ranges.
__global__ void partA(const int* __restrict__ src, const int* __restrict__ dst,
                      const int* __restrict__ part, const int* __restrict__ bsum,
                      unsigned* __restrict__ brec, int E, int chunk, int B) {
    __shared__ int cur[512];
    int t = threadIdx.x, blk = blockIdx.x;
    for (int i = t; i < B; i += 256) {
        int idx = i * NBLK + blk;
        cur[i] = part[idx] + bsum[idx >> 10];
    }
    __syncthreads();
    int e0 = blk * chunk, e1 = min(e0 + chunk, E);
    for (int e = e0 + t; e < e1; e += 256) {
        int s = src[e], d = dst[e];
        int pos = atomicAdd(&cur[d >> 8], 1);
        brec[pos] = ((unsigned)s << 8) | (unsigned)(d & 255);
    }
}

// ---------------- Phase B: per-bucket CSR finalize + u0 = fp16(dinv*x) ----------------
// 1 block = 1 bucket of 256 nodes. Emits row_ptr/adj/dinv/dinv2 AND converts
// its nodes' x rows to u0 = fp16(dinv*x) (tohalf kernel folded in: the
// streaming conversion overlaps the scatter's latency, one fewer dispatch).
__global__ void buildB(const unsigned* __restrict__ brec, const int* __restrict__ part,
                       const int* __restrict__ bsum, int* __restrict__ row_ptr,
                       int* __restrict__ adj, float* __restrict__ dinv,
                       float* __restrict__ dinv2, const float* __restrict__ x,
                       __half* __restrict__ xh, int N, int B, int E) {
    __shared__ int hist[256];
    __shared__ int scanbuf[256];
    __shared__ int cursor[256];
    __shared__ float sdinv[256];
    int t = threadIdx.x, k = blockIdx.x;
    int i0 = k * NBLK;
    int base = part[i0] + bsum[i0 >> 10];
    int nextb;
    if (k + 1 < B) {
        int i1 = (k + 1) * NBLK;
        nextb = part[i1] + bsum[i1 >> 10];
    } else {
        nextb = E;
    }
    hist[t] = 0;
    __syncthreads();
    for (int i = base + t; i < nextb; i += 256) atomicAdd(&hist[brec[i] & 255u], 1);
    __syncthreads();
    int v = hist[t];
    scanbuf[t] = v;
    __syncthreads();
    for (int o = 1; o < 256; o <<= 1) {
        int xx = (t >= o) ? scanbuf[t - o] : 0;
        __syncthreads();
        scanbuf[t] += xx;
        __syncthreads();
    }
    int excl = scanbuf[t] - v;
    int node = k * 256 + t;
    float di = 0.f;
    if (node < N) {
        int p = base + excl;
        row_ptr[node] = p;
        cursor[t] = p;
        float dp1 = (float)v + 1.0f;          // degree incl. self-loop
        di = rsqrtf(dp1);
        dinv[node]  = di;
        dinv2[node] = 1.0f / dp1;
    }
    sdinv[t] = di;
    if (k == 0 && t == 0) row_ptr[N] = E;
    __syncthreads();
    for (int i = base + t; i < nextb; i += 256) {
        unsigned r = brec[i];
        int pos = atomicAdd(&cursor[r & 255u], 1);
        adj[pos] = (int)(r >> 8);
    }
    // fused tohalf for this bucket: 2048 chunks of 8 floats (coalesced)
    int nodeBase = k * 256;
    for (int i = t; i < 2048; i += 256) {
        int nl = i >> 3;
        int node2 = nodeBase + nl;
        if (node2 < N) {
            float d = sdinv[nl];
            size_t baseE = (size_t)node2 * 64 + (size_t)(i & 7) * 8;
            float4 a = *(const float4*)&x[baseE];
            float4 c = *(const float4*)&x[baseE + 4];
            float4 o;
            __half2* op = (__half2*)&o;
            op[0] = __float22half2_rn(make_float2(d * a.x, d * a.y));
            op[1] = __float22half2_rn(make_float2(d * a.z, d * a.w));
            op[2] = __float22half2_rn(make_float2(d * c.x, d * c.y));
            op[3] = __float22half2_rn(make_float2(d * c.z, d * c.w));
            *(float4*)&xh[baseE] = o;
        }
    }
}

// ---------------- propagation: all 4 hops in ONE cooperative kernel ----------------

__device__ __forceinline__ void acc16(float4 hv, float* acc) {
    __half2* hp = (__half2*)&hv;
    #pragma unroll
    for (int i2 = 0; i2 < 4; ++i2) {
        float2 f = __half22float2(hp[i2]);
        acc[2 * i2]     += f.x;
        acc[2 * i2 + 1] += f.y;
    }
}

// One hop: u_out[i] = scale[i] * (u[i] + sum_j u[j]).
// Persistent waves; 2-deep software pipeline on the gather loop plus
// speculative prefetch of the NEXT node's first gather (R6 lesson: metadata
// prefetch alone was neutral -> the limit is gathers-in-flight, so keep 2-3
// float4 gathers outstanding per wave; (256,4) gives the VGPR headroom R6's
// 24-VGPR allocation lacked).
__device__ __forceinline__ void do_hop(const __half* __restrict__ hin,
        __half* __restrict__ hout, const int* __restrict__ row_ptr,
        const int* __restrict__ adj, const float* __restrict__ scale,
        int N, int W, int wid, int lane, int grp, int q) {
    if (wid >= N) return;                 // sync happens in caller
    const float4* hin16 = (const float4*)hin;
    int node = wid;
    int nb = row_ptr[node], ne = row_ptr[node + 1];
    int nadj = adj[nb + lane];            // adj padded by 64 ints
    float nsc = scale[node];
    int jn = __shfl(nadj, grp, 64);       // speculative first-gather prefetch
    int cn = ne - nb;
    float4 pf = hin16[(size_t)((grp < cn) ? jn : 0) * 8 + q];

    while (true) {
        int cur = node, beg = nb, end = ne, myedge = nadj;
        float sc = nsc;
        float4 pf_cur = pf;
        node += W;
        bool more = node < N;
        if (more) {                        // prefetch next node's metadata
            nb = row_ptr[node]; ne = row_ptr[node + 1];
            nadj = adj[nb + lane];
            nsc = scale[node];
        }
        int cnt = end - beg;
        int nit = cnt < 64 ? cnt : 64;

        float acc[8] = {0.f, 0.f, 0.f, 0.f, 0.f, 0.f, 0.f, 0.f};
        if (grp == 0) {                    // self term u[i]
            float4 hv = hin16[(size_t)cur * 8 + q];
            acc16(hv, acc);
        }
        // 2-deep pipelined gather loop
        for (int t = grp; t < nit; t += 8) {
            float4 hv = pf_cur;
            int t2 = t + 8;
            if (t2 < nit) {
                int j2 = __shfl(myedge, t2, 64);
                pf_cur = hin16[(size_t)j2 * 8 + q];
            }
            acc16(hv, acc);
        }
        for (int e = beg + 64 + grp; e < end; e += 8) {   // rare deg>64 tail
            int j = adj[e];
            acc16(hin16[(size_t)j * 8 + q], acc);
        }
        if (more) {                        // next node's first gather, issued
            int jn2 = __shfl(nadj, grp, 64);   // before the butterfly hides it
            int cn2 = ne - nb;
            pf = hin16[(size_t)((grp < cn2) ? jn2 : 0) * 8 + q];
        }
        #pragma unroll
        for (int i = 0; i < 8; ++i) {
            acc[i] += __shfl_xor(acc[i], 8, 64);
            acc[i] += __shfl_xor(acc[i], 16, 64);
            acc[i] += __shfl_xor(acc[i], 32, 64);
        }
        if (grp == 0) {
            float4 o;
            __half2* op = (__half2*)&o;
            op[0] = __float22half2_rn(make_float2(sc * acc[0], sc * acc[1]));
            op[1] = __float22half2_rn(make_float2(sc * acc[2], sc * acc[3]));
            op[2] = __float22half2_rn(make_float2(sc * acc[4], sc * acc[5]));
            op[3] = __float22half2_rn(make_float2(sc * acc[6], sc * acc[7]));
            ((float4*)hout)[(size_t)cur * 8 + q] = o;
        }
        if (!more) return;
    }
}

__global__ void __launch_bounds__(256, 4)
prop_all(const __half* __restrict__ u0, __half* __restrict__ g0,
         __half* __restrict__ g1, const int* __restrict__ row_ptr,
         const int* __restrict__ adj, const float* __restrict__ dinv2,
         const float* __restrict__ dinv, int N, int W) {
    cg::grid_group grid = cg::this_grid();
    int wid  = (blockIdx.x * blockDim.x + threadIdx.x) >> 6;
    int lane = threadIdx.x & 63;
    int grp  = lane >> 3;
    int q    = lane & 7;
    do_hop(u0, g0, row_ptr, adj, dinv2, N, W, wid, lane, grp, q);
    grid.sync();
    do_hop(g0, g1, row_ptr, adj, dinv2, N, W, wid, lane, grp, q);
    grid.sync();
    do_hop(g1, g0, row_ptr, adj, dinv2, N, W, wid, lane, grp, q);
    grid.sync();
    do_hop(g0, g1, row_ptr, adj, dinv,  N, W, wid, lane, grp, q);  // -> g1 = h
}

// ---------------- final: out = 2x + h @ W^T + b - x_pre ----------------
// Register-tiled fp32 GEMM, 64 nodes/block, 4x4 tile/thread.
// __launch_bounds__(256,2) + unroll 8: no spills (R2 lesson).
__global__ void __launch_bounds__(256, 2)
final_kernel(const __half* __restrict__ h, const float* __restrict__ x,
             const float* __restrict__ xp, const float* __restrict__ W,
             const float* __restrict__ b, float* __restrict__ out, int N) {
    __shared__ __align__(16) float ht[64 * 68];
    __shared__ __align__(16) float Wt[64 * 68];
    int t = threadIdx.x;
    int nodeBase = blockIdx.x * 64;

    for (int i = t; i < 1024; i += 256) {
        int c  = i >> 4;
        int k4 = i & 15;
        float4 w4 = ((const float4*)W)[i];
        Wt[(k4 * 4 + 0) * 68 + c] = w4.x;
        Wt[(k4 * 4 + 1) * 68 + c] = w4.y;
        Wt[(k4 * 4 + 2) * 68 + c] = w4.z;
        Wt[(k4 * 4 + 3) * 68 + c] = w4.w;
    }
    for (int i = t; i < 512; i += 256) {
        int n  = i >> 3;
        int k8 = i & 7;
        int node = nodeBase + n;
        float4 hv = (node < N) ? ((const float4*)h)[node * 8 + k8]
                               : make_float4(0.f, 0.f, 0.f, 0.f);
        __half2* hp = (__half2*)&hv;
        #pragma unroll
        for (int j = 0; j < 4; ++j) {
            float2 f = __half22float2(hp[j]);
            ht[(k8 * 8 + 2 * j)     * 68 + n] = f.x;
            ht[(k8 * 8 + 2 * j + 1) * 68 + n] = f.y;
        }
    }
    __syncthreads();

    int r0 = (t >> 4) * 4;
    int c0 = (t & 15) * 4;
    float acc[4][4] = {};
    #pragma unroll 8
    for (int k = 0; k < 64; ++k) {
        float4 hv = *(const float4*)&ht[k * 68 + r0];
        float4 wv = *(const float4*)&Wt[k * 68 + c0];
        acc[0][0] = fmaf(hv.x, wv.x, acc[0][0]);
        acc[0][1] = fmaf(hv.x, wv.y, acc[0][1]);
        acc[0][2] = fmaf(hv.x, wv.z, acc[0][2]);
        acc[0][3] = fmaf(hv.x, wv.w, acc[0][3]);
        acc[1][0] = fmaf(hv.y, wv.x, acc[1][0]);
        acc[1][1] = fmaf(hv.y, wv.y, acc[1][1]);
        acc[1][2] = fmaf(hv.y, wv.z, acc[1][2]);
        acc[1][3] = fmaf(hv.y, wv.w, acc[1][3]);
        acc[2][0] = fmaf(hv.z, wv.x, acc[2][0]);
        acc[2][1] = fmaf(hv.z, wv.y, acc[2][1]);
        acc[2][2] = fmaf(hv.z, wv.z, acc[2][2]);
        acc[2][3] = fmaf(hv.z, wv.w, acc[2][3]);
        acc[3][0] = fmaf(hv.w, wv.x, acc[3][0]);
        acc[3][1] = fmaf(hv.w, wv.y, acc[3][1]);
        acc[3][2] = fmaf(hv.w, wv.z, acc[3][2]);
        acc[3][3] = fmaf(hv.w, wv.w, acc[3][3]);
    }

    float4 bv = *(const float4*)&b[c0];
    #pragma unroll
    for (int i = 0; i < 4; ++i) {
        int node = nodeBase + r0 + i;
        if (node >= N) continue;
        int base = node * 64 + c0;
        float4 xv = *(const float4*)&x[base];
        float4 pv = *(const float4*)&xp[base];
        float4 o;
        o.x = fmaf(2.f, xv.x, acc[i][0] + bv.x) - pv.x;
        o.y = fmaf(2.f, xv.y, acc[i][1] + bv.y) - pv.y;
        o.z = fmaf(2.f, xv.z, acc[i][2] + bv.z) - pv.z;
        o.w = fmaf(2.f, xv.w, acc[i][3] + bv.w) - pv.w;
        *(float4*)&out[base] = o;
    }
}

extern "C" void kernel_launch(void* const* d_in, const int* in_sizes, int n_in,
                              void* d_out, int out_size, void* d_ws, size_t ws_size,
                              hipStream_t stream) {
    const float* x    = (const float*)d_in[0];
    const float* xpre = (const float*)d_in[1];
    const int*   ei   = (const int*)d_in[2];
    const float* W    = (const float*)d_in[3];
    const float* b    = (const float*)d_in[4];
    float* out = (float*)d_out;

    int N = in_sizes[0] / CCH;
    const int E = in_sizes[2] / 2;
    const int* src = ei;
    const int* dst = ei + E;

    const int B     = (N + BKT - 1) / BKT;       // buckets
    const int M     = B * NBLK;                  // count-matrix size
    const int chunk = (E + NBLK - 1) / NBLK;
    const int NB2   = (M + 1023) / 1024;         // scan1 blocks

    // workspace partition (256B aligned)
    char* p = (char*)d_ws;
    auto alloc = [&](size_t bytes) -> char* {
        char* r = p;
        p += (bytes + 255) & ~(size_t)255;
        return r;
    };
    int*      cntmat  = (int*)alloc((size_t)M * 4);
    int*      part    = (int*)alloc((size_t)M * 4);
    int*      bsum    = (int*)alloc((size_t)NB2 * 4);
    unsigned* brec    = (unsigned*)alloc((size_t)E * 4);
    int*      adj     = (int*)alloc(((size_t)E + 64) * 4);
    int*      row_ptr = (int*)alloc(((size_t)N + 1) * 4);
    float*    dinv    = (float*)alloc((size_t)N * 4);
    float*    dinv2   = (float*)alloc((size_t)N * 4);
    __half*   xh      = (__half*)alloc((size_t)N * CCH * 2);
    __half*   g0      = (__half*)alloc((size_t)N * CCH * 2);
    __half*   g1      = (__half*)alloc((size_t)N * CCH * 2);

    countA<<<NBLK, 256, 0, stream>>>(dst, cntmat, E, chunk, B);
    scan1 <<<NB2, 256, 0, stream>>>(cntmat, part, bsum, M);
    scan2 <<<1, 256, 0, stream>>>(bsum, NB2);
    partA <<<NBLK, 256, 0, stream>>>(src, dst, part, bsum, brec, E, chunk, B);
    buildB<<<B, 256, 0, stream>>>(brec, part, bsum, row_ptr, adj, dinv, dinv2,
                                  x, xh, N, B, E);

    // cooperative 4-hop propagation: grid must be fully co-resident
    int maxb = 0;
    if (hipOccupancyMaxActiveBlocksPerMultiprocessor(&maxb, prop_all, 256, 0)
            != hipSuccess || maxb < 1) maxb = 4;
    if (maxb > 4) maxb = 4;
    int PBLK = maxb * 256;                 // blocks co-resident on 256 CUs
    int Wv   = PBLK * 4;                   // total waves
    void* args[] = {(void*)&xh, (void*)&g0, (void*)&g1, (void*)&row_ptr,
                    (void*)&adj, (void*)&dinv2, (void*)&dinv,
                    (void*)&N, (void*)&Wv};
    hipLaunchCooperativeKernel((void*)prop_all, dim3(PBLK), dim3(256),
                               args, 0, stream);

    final_kernel<<<(N + 63) / 64, 256, 0, stream>>>(g1, x, xpre, W, b, out, N);
}

// Round 8
// 286.318 us; speedup vs baseline: 2.5181x; 2.5181x over previous
//
#include <hip/hip_runtime.h>
#include <hip/hip_fp16.h>

#define CCH 64
#define NBLK 128        // phase-A partition blocks
#define BKT  256        // nodes per bucket

// ---------------- Phase A: partitioned counting sort of edges by dst ----------------

__global__ void countA(const int* __restrict__ dst, int* __restrict__ cntmat,
                       int E, int chunk, int B) {
    __shared__ int h[512];
    int t = threadIdx.x, blk = blockIdx.x;
    for (int i = t; i < B; i += 256) h[i] = 0;
    __syncthreads();
    int e0 = blk * chunk, e1 = min(e0 + chunk, E);
    for (int e = e0 + t; e < e1; e += 256) atomicAdd(&h[dst[e] >> 8], 1);
    __syncthreads();
    for (int i = t; i < B; i += 256) cntmat[i * NBLK + blk] = h[i];
}

// Two-level exclusive scan (1024 elems / block)
__global__ void scan1(const int* __restrict__ cnt, int* __restrict__ part,
                      int* __restrict__ bsum, int N) {
    __shared__ int s[256];
    int t = threadIdx.x;
    int base = blockIdx.x * 1024 + t * 4;
    int v0 = (base + 0 < N) ? cnt[base + 0] : 0;
    int v1 = (base + 1 < N) ? cnt[base + 1] : 0;
    int v2 = (base + 2 < N) ? cnt[base + 2] : 0;
    int v3 = (base + 3 < N) ? cnt[base + 3] : 0;
    s[t] = v0 + v1 + v2 + v3;
    __syncthreads();
    for (int off = 1; off < 256; off <<= 1) {
        int xx = (t >= off) ? s[t - off] : 0;
        __syncthreads();
        s[t] += xx;
        __syncthreads();
    }
    int excl = (t == 0) ? 0 : s[t - 1];
    if (t == 255) bsum[blockIdx.x] = s[255];
    if (base + 0 < N) part[base + 0] = excl;
    if (base + 1 < N) part[base + 1] = excl + v0;
    if (base + 2 < N) part[base + 2] = excl + v0 + v1;
    if (base + 3 < N) part[base + 3] = excl + v0 + v1 + v2;
}

__global__ void scan2(int* __restrict__ bsum, int NB) {
    __shared__ int s[256];
    int t = threadIdx.x;
    int base = t * 4;
    int v0 = (base + 0 < NB) ? bsum[base + 0] : 0;
    int v1 = (base + 1 < NB) ? bsum[base + 1] : 0;
    int v2 = (base + 2 < NB) ? bsum[base + 2] : 0;
    int v3 = (base + 3 < NB) ? bsum[base + 3] : 0;
    s[t] = v0 + v1 + v2 + v3;
    __syncthreads();
    for (int off = 1; off < 256; off <<= 1) {
        int xx = (t >= off) ? s[t - off] : 0;
        __syncthreads();
        s[t] += xx;
        __syncthreads();
    }
    int excl = (t == 0) ? 0 : s[t - 1];
    if (base + 0 < NB) bsum[base + 0] = excl;
    if (base + 1 < NB) bsum[base + 1] = excl + v0;
    if (base + 2 < NB) bsum[base + 2] = excl + v0 + v1;
    if (base + 3 < NB) bsum[base + 3] = excl + v0 + v1 + v2;
}

// partition: write (src<<8 | dst&255) into per-(block,bucket) exclusive ranges.
__global__ void partA(const int* __restrict__ src, const int* __restrict__ dst,
                      const int* __restrict__ part, const int* __restrict__ bsum,
                      unsigned* __restrict__ brec, int E, int chunk, int B) {
    __shared__ int cur[512];
    int t = threadIdx.x, blk = blockIdx.x;
    for (int i = t; i < B; i += 256) {
        int idx = i * NBLK + blk;
        cur[i] = part[idx] + bsum[idx >> 10];
    }
    __syncthreads();
    int e0 = blk * chunk, e1 = min(e0 + chunk, E);
    for (int e = e0 + t; e < e1; e += 256) {
        int s = src[e], d = dst[e];
        int pos = atomicAdd(&cur[d >> 8], 1);
        brec[pos] = ((unsigned)s << 8) | (unsigned)(d & 255);
    }
}

// ---------------- Phase B: per-bucket CSR finalize + u0 = fp16(dinv*x) ----------------
__global__ void buildB(const unsigned* __restrict__ brec, const int* __restrict__ part,
                       const int* __restrict__ bsum, int* __restrict__ row_ptr,
                       int* __restrict__ adj, float* __restrict__ dinv,
                       float* __restrict__ dinv2, const float* __restrict__ x,
                       __half* __restrict__ xh, int N, int B, int E) {
    __shared__ int hist[256];
    __shared__ int scanbuf[256];
    __shared__ int cursor[256];
    __shared__ float sdinv[256];
    int t = threadIdx.x, k = blockIdx.x;
    int i0 = k * NBLK;
    int base = part[i0] + bsum[i0 >> 10];
    int nextb;
    if (k + 1 < B) {
        int i1 = (k + 1) * NBLK;
        nextb = part[i1] + bsum[i1 >> 10];
    } else {
        nextb = E;
    }
    hist[t] = 0;
    __syncthreads();
    for (int i = base + t; i < nextb; i += 256) atomicAdd(&hist[brec[i] & 255u], 1);
    __syncthreads();
    int v = hist[t];
    scanbuf[t] = v;
    __syncthreads();
    for (int o = 1; o < 256; o <<= 1) {
        int xx = (t >= o) ? scanbuf[t - o] : 0;
        __syncthreads();
        scanbuf[t] += xx;
        __syncthreads();
    }
    int excl = scanbuf[t] - v;
    int node = k * 256 + t;
    float di = 0.f;
    if (node < N) {
        int p = base + excl;
        row_ptr[node] = p;
        cursor[t] = p;
        float dp1 = (float)v + 1.0f;          // degree incl. self-loop
        di = rsqrtf(dp1);
        dinv[node]  = di;
        dinv2[node] = 1.0f / dp1;
    }
    sdinv[t] = di;
    if (k == 0 && t == 0) row_ptr[N] = E;
    __syncthreads();
    for (int i = base + t; i < nextb; i += 256) {
        unsigned r = brec[i];
        int pos = atomicAdd(&cursor[r & 255u], 1);
        adj[pos] = (int)(r >> 8);
    }
    // fused tohalf for this bucket (coalesced; overlaps scatter latency)
    int nodeBase = k * 256;
    for (int i = t; i < 2048; i += 256) {
        int nl = i >> 3;
        int node2 = nodeBase + nl;
        if (node2 < N) {
            float d = sdinv[nl];
            size_t baseE = (size_t)node2 * 64 + (size_t)(i & 7) * 8;
            float4 a = *(const float4*)&x[baseE];
            float4 c = *(const float4*)&x[baseE + 4];
            float4 o;
            __half2* op = (__half2*)&o;
            op[0] = __float22half2_rn(make_float2(d * a.x, d * a.y));
            op[1] = __float22half2_rn(make_float2(d * a.z, d * a.w));
            op[2] = __float22half2_rn(make_float2(d * c.x, d * c.y));
            op[3] = __float22half2_rn(make_float2(d * c.z, d * c.w));
            *(float4*)&xh[baseE] = o;
        }
    }
}

// ---------------- propagation: u_out[i] = scale[i] * (u[i] + sum_j u[j]) ----------------
// TWO nodes per wave, interleaved (R7 lesson: coop sync is poison; R6 lesson:
// the limiter is gathers-in-flight per wave, ~1). Nodes nA=2w, nB=2w+1 have
// contiguous adj ranges; each round issues A's and B's next gathers
// back-to-back before accumulating the current pair -> 2 independent float4
// gathers in flight during every accumulate phase. Invalid slots load the
// L1-hot row 0 and are killed by a 0/1 fma weight (branchless, no divergence).

__device__ __forceinline__ void acc16w(float4 hv, float w, float* acc) {
    __half2* hp = (__half2*)&hv;
    #pragma unroll
    for (int i2 = 0; i2 < 4; ++i2) {
        float2 f = __half22float2(hp[i2]);
        acc[2 * i2]     = fmaf(w, f.x, acc[2 * i2]);
        acc[2 * i2 + 1] = fmaf(w, f.y, acc[2 * i2 + 1]);
    }
}

__global__ void __launch_bounds__(256, 6)
prop_kernel(const __half* __restrict__ hin, __half* __restrict__ hout,
            const int* __restrict__ row_ptr, const int* __restrict__ adj,
            const float* __restrict__ scale, int N) {
    int wid = (blockIdx.x * blockDim.x + threadIdx.x) >> 6;
    int nA = wid * 2;
    if (nA >= N) return;
    int nB = nA + 1;
    bool hasB = nB < N;
    int lane = threadIdx.x & 63;
    int grp  = lane >> 3;
    int q    = lane & 7;
    const float4* hin16 = (const float4*)hin;

    int rp0 = row_ptr[nA];
    int rp1 = row_ptr[nA + 1];
    int rp2 = hasB ? row_ptr[nA + 2] : rp1;
    int begA = rp0, cntA = rp1 - rp0;
    int begB = rp1, cntB = rp2 - rp1;
    int edA = adj[begA + lane];          // adj padded by 64 ints
    int edB = adj[begB + lane];
    float scA = scale[nA];
    float scB = hasB ? scale[nB] : 0.f;

    // self row (grp0 -> A, grp1 -> B) + round-0 gathers: 3 loads in flight
    int selfn = (grp == 0) ? nA : ((grp == 1 && hasB) ? nB : 0);
    float4 selfv = hin16[(size_t)selfn * 8 + q];
    int nitA = cntA < 64 ? cntA : 64;
    int nitB = cntB < 64 ? cntB : 64;
    int jA0 = __shfl(edA, grp, 64);
    int jB0 = __shfl(edB, grp, 64);
    float4 pfA = hin16[(size_t)((grp < nitA) ? jA0 : 0) * 8 + q];
    float4 pfB = hin16[(size_t)((grp < nitB) ? jB0 : 0) * 8 + q];

    float accA[8] = {0.f, 0.f, 0.f, 0.f, 0.f, 0.f, 0.f, 0.f};
    float accB[8] = {0.f, 0.f, 0.f, 0.f, 0.f, 0.f, 0.f, 0.f};
    if (grp == 0)              acc16w(selfv, 1.f, accA);
    else if (grp == 1 && hasB) acc16w(selfv, 1.f, accB);

    int RA = (nitA + 7) >> 3;
    int RB = (nitB + 7) >> 3;
    int R  = RA > RB ? RA : RB;          // wave-uniform round count (<= 8)
    for (int r = 0; r < R; ++r) {
        float4 cA = pfA, cB = pfB;
        float wA = (r * 8 + grp < nitA) ? 1.f : 0.f;
        float wB = (r * 8 + grp < nitB) ? 1.f : 0.f;
        if (r + 1 < R) {                 // uniform: issue next round's pair now
            int t1 = (r + 1) * 8 + grp;  // <= 63
            int jA = __shfl(edA, t1, 64);
            int jB = __shfl(edB, t1, 64);
            pfA = hin16[(size_t)((t1 < nitA) ? jA : 0) * 8 + q];
            pfB = hin16[(size_t)((t1 < nitB) ? jB : 0) * 8 + q];
        }
        acc16w(cA, wA, accA);
        acc16w(cB, wB, accB);
    }
    for (int e = begA + 64 + grp; e < begA + cntA; e += 8)   // rare deg>64 tails
        acc16w(hin16[(size_t)adj[e] * 8 + q], 1.f, accA);
    for (int e = begB + 64 + grp; e < begB + cntB; e += 8)
        acc16w(hin16[(size_t)adj[e] * 8 + q], 1.f, accB);

    #pragma unroll
    for (int i = 0; i < 8; ++i) {
        accA[i] += __shfl_xor(accA[i], 8, 64);
        accA[i] += __shfl_xor(accA[i], 16, 64);
        accA[i] += __shfl_xor(accA[i], 32, 64);
        accB[i] += __shfl_xor(accB[i], 8, 64);
        accB[i] += __shfl_xor(accB[i], 16, 64);
        accB[i] += __shfl_xor(accB[i], 32, 64);
    }
    if (grp == 0 || (grp == 1 && hasB)) {   // both rows stored in ONE instruction
        int   row = (grp == 0) ? nA : nB;
        float sc  = (grp == 0) ? scA : scB;
        float v0 = (grp == 0) ? accA[0] : accB[0];
        float v1 = (grp == 0) ? accA[1] : accB[1];
        float v2 = (grp == 0) ? accA[2] : accB[2];
        float v3 = (grp == 0) ? accA[3] : accB[3];
        float v4 = (grp == 0) ? accA[4] : accB[4];
        float v5 = (grp == 0) ? accA[5] : accB[5];
        float v6 = (grp == 0) ? accA[6] : accB[6];
        float v7 = (grp == 0) ? accA[7] : accB[7];
        float4 o;
        __half2* op = (__half2*)&o;
        op[0] = __float22half2_rn(make_float2(sc * v0, sc * v1));
        op[1] = __float22half2_rn(make_float2(sc * v2, sc * v3));
        op[2] = __float22half2_rn(make_float2(sc * v4, sc * v5));
        op[3] = __float22half2_rn(make_float2(sc * v6, sc * v7));
        ((float4*)hout)[(size_t)row * 8 + q] = o;
    }
}

// ---------------- final: out = 2x + h @ W^T + b - x_pre ----------------
__global__ void __launch_bounds__(256, 2)
final_kernel(const __half* __restrict__ h, const float* __restrict__ x,
             const float* __restrict__ xp, const float* __restrict__ W,
             const float* __restrict__ b, float* __restrict__ out, int N) {
    __shared__ __align__(16) float ht[64 * 68];
    __shared__ __align__(16) float Wt[64 * 68];
    int t = threadIdx.x;
    int nodeBase = blockIdx.x * 64;

    for (int i = t; i < 1024; i += 256) {
        int c  = i >> 4;
        int k4 = i & 15;
        float4 w4 = ((const float4*)W)[i];
        Wt[(k4 * 4 + 0) * 68 + c] = w4.x;
        Wt[(k4 * 4 + 1) * 68 + c] = w4.y;
        Wt[(k4 * 4 + 2) * 68 + c] = w4.z;
        Wt[(k4 * 4 + 3) * 68 + c] = w4.w;
    }
    for (int i = t; i < 512; i += 256) {
        int n  = i >> 3;
        int k8 = i & 7;
        int node = nodeBase + n;
        float4 hv = (node < N) ? ((const float4*)h)[node * 8 + k8]
                               : make_float4(0.f, 0.f, 0.f, 0.f);
        __half2* hp = (__half2*)&hv;
        #pragma unroll
        for (int j = 0; j < 4; ++j) {
            float2 f = __half22float2(hp[j]);
            ht[(k8 * 8 + 2 * j)     * 68 + n] = f.x;
            ht[(k8 * 8 + 2 * j + 1) * 68 + n] = f.y;
        }
    }
    __syncthreads();

    int r0 = (t >> 4) * 4;
    int c0 = (t & 15) * 4;
    float acc[4][4] = {};
    #pragma unroll 8
    for (int k = 0; k < 64; ++k) {
        float4 hv = *(const float4*)&ht[k * 68 + r0];
        float4 wv = *(const float4*)&Wt[k * 68 + c0];
        acc[0][0] = fmaf(hv.x, wv.x, acc[0][0]);
        acc[0][1] = fmaf(hv.x, wv.y, acc[0][1]);
        acc[0][2] = fmaf(hv.x, wv.z, acc[0][2]);
        acc[0][3] = fmaf(hv.x, wv.w, acc[0][3]);
        acc[1][0] = fmaf(hv.y, wv.x, acc[1][0]);
        acc[1][1] = fmaf(hv.y, wv.y, acc[1][1]);
        acc[1][2] = fmaf(hv.y, wv.z, acc[1][2]);
        acc[1][3] = fmaf(hv.y, wv.w, acc[1][3]);
        acc[2][0] = fmaf(hv.z, wv.x, acc[2][0]);
        acc[2][1] = fmaf(hv.z, wv.y, acc[2][1]);
        acc[2][2] = fmaf(hv.z, wv.z, acc[2][2]);
        acc[2][3] = fmaf(hv.z, wv.w, acc[2][3]);
        acc[3][0] = fmaf(hv.w, wv.x, acc[3][0]);
        acc[3][1] = fmaf(hv.w, wv.y, acc[3][1]);
        acc[3][2] = fmaf(hv.w, wv.z, acc[3][2]);
        acc[3][3] = fmaf(hv.w, wv.w, acc[3][3]);
    }

    float4 bv = *(const float4*)&b[c0];
    #pragma unroll
    for (int i = 0; i < 4; ++i) {
        int node = nodeBase + r0 + i;
        if (node >= N) continue;
        int base = node * 64 + c0;
        float4 xv = *(const float4*)&x[base];
        float4 pv = *(const float4*)&xp[base];
        float4 o;
        o.x = fmaf(2.f, xv.x, acc[i][0] + bv.x) - pv.x;
        o.y = fmaf(2.f, xv.y, acc[i][1] + bv.y) - pv.y;
        o.z = fmaf(2.f, xv.z, acc[i][2] + bv.z) - pv.z;
        o.w = fmaf(2.f, xv.w, acc[i][3] + bv.w) - pv.w;
        *(float4*)&out[base] = o;
    }
}

extern "C" void kernel_launch(void* const* d_in, const int* in_sizes, int n_in,
                              void* d_out, int out_size, void* d_ws, size_t ws_size,
                              hipStream_t stream) {
    const float* x    = (const float*)d_in[0];
    const float* xpre = (const float*)d_in[1];
    const int*   ei   = (const int*)d_in[2];
    const float* W    = (const float*)d_in[3];
    const float* b    = (const float*)d_in[4];
    float* out = (float*)d_out;

    const int N = in_sizes[0] / CCH;
    const int E = in_sizes[2] / 2;
    const int* src = ei;
    const int* dst = ei + E;

    const int B     = (N + BKT - 1) / BKT;       // buckets
    const int M     = B * NBLK;                  // count-matrix size
    const int chunk = (E + NBLK - 1) / NBLK;
    const int NB2   = (M + 1023) / 1024;         // scan1 blocks

    // workspace partition (256B aligned)
    char* p = (char*)d_ws;
    auto alloc = [&](size_t bytes) -> char* {
        char* r = p;
        p += (bytes + 255) & ~(size_t)255;
        return r;
    };
    int*      cntmat  = (int*)alloc((size_t)M * 4);
    int*      part    = (int*)alloc((size_t)M * 4);
    int*      bsum    = (int*)alloc((size_t)NB2 * 4);
    unsigned* brec    = (unsigned*)alloc((size_t)E * 4);
    int*      adj     = (int*)alloc(((size_t)E + 64) * 4);
    int*      row_ptr = (int*)alloc(((size_t)N + 1) * 4);
    float*    dinv    = (float*)alloc((size_t)N * 4);
    float*    dinv2   = (float*)alloc((size_t)N * 4);
    __half*   xh      = (__half*)alloc((size_t)N * CCH * 2);
    __half*   g0      = (__half*)alloc((size_t)N * CCH * 2);
    __half*   g1      = (__half*)alloc((size_t)N * CCH * 2);

    countA<<<NBLK, 256, 0, stream>>>(dst, cntmat, E, chunk, B);
    scan1 <<<NB2, 256, 0, stream>>>(cntmat, part, bsum, M);
    scan2 <<<1, 256, 0, stream>>>(bsum, NB2);
    partA <<<NBLK, 256, 0, stream>>>(src, dst, part, bsum, brec, E, chunk, B);
    buildB<<<B, 256, 0, stream>>>(brec, part, bsum, row_ptr, adj, dinv, dinv2,
                                  x, xh, N, B, E);

    const int nw    = (N + 1) / 2;               // 2 nodes per wave
    const int pgrid = (nw + 3) / 4;              // 4 waves per 256-thread block
    prop_kernel<<<pgrid, 256, 0, stream>>>(xh, g0, row_ptr, adj, dinv2, N); // hop 1
    prop_kernel<<<pgrid, 256, 0, stream>>>(g0, g1, row_ptr, adj, dinv2, N); // hop 2
    prop_kernel<<<pgrid, 256, 0, stream>>>(g1, g0, row_ptr, adj, dinv2, N); // hop 3
    prop_kernel<<<pgrid, 256, 0, stream>>>(g0, g1, row_ptr, adj, dinv,  N); // hop 4 -> g1=h

    final_kernel<<<(N + 63) / 64, 256, 0, stream>>>(g1, x, xpre, W, b, out, N);
}